// Round 3
// baseline (505.048 us; speedup 1.0000x reference)
//
#include <hip/hip_runtime.h>
#include <stdint.h>

// LSTM cell, fp32 I/O: z = x@Wx + h@Wh + bx + bh (M=32768, N=4*512, K=1024)
// fused with gate activations and C/h update. No fp32 MFMA on CDNA4 ->
// downcast x,h,W to bf16 for the matrix cores, accumulate fp32 (harness
// threshold 8.8e-2 is bf16-scaled to permit exactly this).
// R3: dtype flip. R0-R2 NaN diagnosis: buffers are fp32; reading them as
// bf16 yields ~0.4% NaN/Inf bit patterns in odd halves -> acc NaN.

#define BROWS 32768
#define DH 512
#define KTOT 1024   // D_IN + D_H
#define BM 128
#define BK 64

typedef __attribute__((ext_vector_type(8))) __bf16 bf16x8;
typedef __attribute__((ext_vector_type(4))) float f32x4;

__device__ __forceinline__ float sigf(float v)  { return 1.0f / (1.0f + __expf(-v)); }
__device__ __forceinline__ float tanhf_(float v){ return 1.0f - 2.0f / (1.0f + __expf(2.0f * v)); }

// Wt[(jb*128 + r)*1024 + k] (bf16) where r = (hl>>4)*64 + g*16 + (hl&15),
// source col n = g*512 + jb*32 + hl, row k (k<512 -> Wx, else Wh). Also
// performs the fp32->bf16 downcast.
__global__ void pack_w(const float* __restrict__ Wx, const float* __restrict__ Wh,
                       __bf16* __restrict__ Wt) {
  int o  = blockIdx.x * 256 + threadIdx.x;   // 0 .. 2M
  int k  = o & (KTOT - 1);
  int rg = o >> 10;          // packed row 0..2047
  int jb = rg >> 7;
  int r  = rg & 127;
  int g  = (r >> 4) & 3;
  int hl = ((r >> 6) << 4) | (r & 15);
  int n  = g * DH + jb * 32 + hl;
  float v = (k < DH) ? Wx[k * 4 * DH + n] : Wh[(k - DH) * 4 * DH + n];
  Wt[o] = (__bf16)v;
}

__global__ __launch_bounds__(256, 3) void lstm_gemm(
    const float* __restrict__ x, const float* __restrict__ h,
    const __bf16* __restrict__ Wt, const float* __restrict__ bx,
    const float* __restrict__ bh, const float* __restrict__ Cin,
    float* __restrict__ out) {
  __shared__ __attribute__((aligned(16))) __bf16 As[BM * BK];  // 16 KB
  __shared__ __attribute__((aligned(16))) __bf16 Bs[BM * BK];  // 16 KB

  const int tid  = threadIdx.x;
  const int lane = tid & 63;
  const int wave = tid >> 6;
  const int wm = wave >> 1, wn = wave & 1;   // 2x2 waves over (M, N)
  const int jb   = blockIdx.x;               // 0..15 hidden-block
  const int bm   = blockIdx.y;               // 0..255 row-block
  const int row0 = bm * BM;

  const __bf16* Bt = Wt + (size_t)jb * 128 * KTOT;

  f32x4 acc[4][4];   // acc[cm][gate]
  #pragma unroll
  for (int a_ = 0; a_ < 4; ++a_)
    #pragma unroll
    for (int b_ = 0; b_ < 4; ++b_) acc[a_][b_] = (f32x4)0.0f;

  for (int k0 = 0; k0 < KTOT; k0 += BK) {
    const float* Aptr = (k0 < DH) ? (x + (size_t)row0 * DH + k0)
                                  : (h + (size_t)row0 * DH + (k0 - DH));
    // ---- stage A (fp32 -> bf16 cvt) and B (bf16) into LDS
    bf16x8 ta[4], tb[4];
    #pragma unroll
    for (int it = 0; it < 4; ++it) {
      int lin = it * 256 + tid;
      int r = lin >> 3, c8 = lin & 7;
      const float* src = Aptr + r * DH + c8 * 8;
      float4 f0 = *(const float4*)src;
      float4 f1 = *(const float4*)(src + 4);
      bf16x8 v;
      v[0] = (__bf16)f0.x; v[1] = (__bf16)f0.y;
      v[2] = (__bf16)f0.z; v[3] = (__bf16)f0.w;
      v[4] = (__bf16)f1.x; v[5] = (__bf16)f1.y;
      v[6] = (__bf16)f1.z; v[7] = (__bf16)f1.w;
      ta[it] = v;
    }
    #pragma unroll
    for (int it = 0; it < 4; ++it) {
      int lin = it * 256 + tid;
      int r = lin >> 3, c8 = lin & 7;
      tb[it] = *(const bf16x8*)(Bt + (size_t)r * KTOT + k0 + c8 * 8);
    }
    #pragma unroll
    for (int it = 0; it < 4; ++it) {
      int lin = it * 256 + tid;
      *(bf16x8*)&As[lin * 8] = ta[it];
      *(bf16x8*)&Bs[lin * 8] = tb[it];
    }
    __syncthreads();

    #pragma unroll
    for (int ks = 0; ks < 2; ++ks) {
      const int ko = ks * 32 + (lane >> 4) * 8;
      bf16x8 af[4], bfr[4];
      #pragma unroll
      for (int cm = 0; cm < 4; ++cm)
        af[cm] = *(const bf16x8*)&As[(wm * 64 + cm * 16 + (lane & 15)) * BK + ko];
      #pragma unroll
      for (int cn = 0; cn < 4; ++cn)
        bfr[cn] = *(const bf16x8*)&Bs[(wn * 64 + cn * 16 + (lane & 15)) * BK + ko];
      #pragma unroll
      for (int cm = 0; cm < 4; ++cm)
        #pragma unroll
        for (int cn = 0; cn < 4; ++cn)
          acc[cm][cn] = __builtin_amdgcn_mfma_f32_16x16x32_bf16(
              af[cm], bfr[cn], acc[cm][cn], 0, 0, 0);
    }
    __syncthreads();
  }

  // ---- fused LSTM epilogue: lane holds 4 gates of hid `hd` for 16 rows ----
  const int hd = jb * 32 + wn * 16 + (lane & 15);
  float bias[4];
  #pragma unroll
  for (int g2 = 0; g2 < 4; ++g2)
    bias[g2] = bx[g2 * DH + hd] + bh[g2 * DH + hd];

  #pragma unroll
  for (int cm = 0; cm < 4; ++cm) {
    const int rbase = row0 + wm * 64 + cm * 16 + (lane >> 4) * 4;
    #pragma unroll
    for (int i2 = 0; i2 < 4; ++i2) {
      const size_t r = (size_t)(rbase + i2);
      float ig = sigf(acc[cm][0][i2] + bias[0]);
      float fg = sigf(acc[cm][1][i2] + bias[1]);
      float og = sigf(acc[cm][2][i2] + bias[2]);
      float gg = tanhf_(acc[cm][3][i2] + bias[3]);
      float cp = Cin[r * DH + hd];
      float cnew = fg * cp + ig * gg;
      float hnew = og * tanhf_(cnew);
      out[r * DH + hd] = cnew;
      out[(size_t)BROWS * DH + r * DH + hd] = hnew;
    }
  }
}

// Safety-net path if workspace is too small for Wt (4 MB): slow but correct.
__global__ void lstm_naive(const float* __restrict__ x, const float* __restrict__ Cin,
                           const float* __restrict__ h, const float* __restrict__ Wx,
                           const float* __restrict__ bxp, const float* __restrict__ Wh,
                           const float* __restrict__ bhp, float* __restrict__ out) {
  int idx = blockIdx.x * 256 + threadIdx.x;
  int r = idx >> 9, hd = idx & 511;
  float z[4];
  #pragma unroll
  for (int g = 0; g < 4; ++g)
    z[g] = bxp[g * DH + hd] + bhp[g * DH + hd];
  for (int k = 0; k < DH; ++k) {
    float xv = x[(size_t)r * DH + k];
    #pragma unroll
    for (int g = 0; g < 4; ++g) z[g] += xv * Wx[k * 4 * DH + g * DH + hd];
  }
  for (int k = 0; k < DH; ++k) {
    float hv = h[(size_t)r * DH + k];
    #pragma unroll
    for (int g = 0; g < 4; ++g) z[g] += hv * Wh[k * 4 * DH + g * DH + hd];
  }
  float ig = sigf(z[0]), fg = sigf(z[1]), og = sigf(z[2]), gg = tanhf_(z[3]);
  float cp = Cin[(size_t)r * DH + hd];
  float cnew = fg * cp + ig * gg;
  float hnew = og * tanhf_(cnew);
  out[(size_t)r * DH + hd] = cnew;
  out[(size_t)BROWS * DH + (size_t)r * DH + hd] = hnew;
}

extern "C" void kernel_launch(void* const* d_in, const int* in_sizes, int n_in,
                              void* d_out, int out_size, void* d_ws, size_t ws_size,
                              hipStream_t stream) {
  const float* x  = (const float*)d_in[0];
  const float* Ci = (const float*)d_in[1];
  const float* h  = (const float*)d_in[2];
  const float* Wx = (const float*)d_in[3];
  const float* bx = (const float*)d_in[4];
  const float* Wh = (const float*)d_in[5];
  const float* bh = (const float*)d_in[6];
  float* out = (float*)d_out;

  const size_t need = (size_t)2048 * KTOT * sizeof(__bf16);  // 4 MB
  if (ws_size >= need) {
    __bf16* Wt = (__bf16*)d_ws;
    pack_w<<<dim3((2048 * KTOT) / 256), dim3(256), 0, stream>>>(Wx, Wh, Wt);
    lstm_gemm<<<dim3(16, 256), dim3(256), 0, stream>>>(x, h, Wt, bx, bh, Ci, out);
  } else {
    lstm_naive<<<dim3((BROWS * DH) / 256), dim3(256), 0, stream>>>(
        x, Ci, h, Wx, bx, Wh, bh, out);
  }
}

// Round 4
// 428.986 us; speedup vs baseline: 1.1773x; 1.1773x over previous
//
#include <hip/hip_runtime.h>
#include <stdint.h>

// LSTM cell, fp32 I/O: z = x@Wx + h@Wh + bx + bh (M=32768, N=2048, K=1024)
// fused with gate activations and C/h update. bf16 MFMA, fp32 accumulate.
// R4: (a) coalesced LDS-transpose pack (~170us -> ~10us);
//     (b) bf16 pre-cast of [x|h] so the K-loop stages pure bf16;
//     (c) m97-style global_load_lds(16B) staging with XOR chunk swizzle ->
//         conflict-free ds_read_b128 fragments (R3: 5e7 bank-conflict cycles).

#define BROWS 32768
#define DH 512
#define KTOT 1024   // D_IN + D_H
#define BM 128
#define BK 64

typedef __attribute__((ext_vector_type(8))) __bf16 bf16x8;
typedef __attribute__((ext_vector_type(4))) float f32x4;
typedef __attribute__((address_space(1))) void gvoid;
typedef __attribute__((address_space(3))) void lvoid;

__device__ __forceinline__ void gl_lds16(const void* g, void* l) {
  __builtin_amdgcn_global_load_lds((gvoid*)g, (lvoid*)l, 16, 0, 0);
}

__device__ __forceinline__ float sigf(float v)  { return 1.0f / (1.0f + __expf(-v)); }
__device__ __forceinline__ float tanhf_(float v){ return 1.0f - 2.0f / (1.0f + __expf(2.0f * v)); }

// ---- pre-pass: xh[r][c] = bf16(c<512 ? x[r][c] : h[r][c-512]), coalesced ----
__global__ void conv_xh(const float* __restrict__ x, const float* __restrict__ h,
                        __bf16* __restrict__ xh) {
  int o = blockIdx.x * 256 + threadIdx.x;       // chunk of 8 elems
  int c = (o & 127) * 8;
  int r = o >> 7;
  const float* src = (c < DH) ? (x + (size_t)r * DH + c)
                              : (h + (size_t)r * DH + (c - DH));
  float4 f0 = *(const float4*)src;
  float4 f1 = *(const float4*)(src + 4);
  bf16x8 v;
  v[0] = (__bf16)f0.x; v[1] = (__bf16)f0.y; v[2] = (__bf16)f0.z; v[3] = (__bf16)f0.w;
  v[4] = (__bf16)f1.x; v[5] = (__bf16)f1.y; v[6] = (__bf16)f1.z; v[7] = (__bf16)f1.w;
  *(bf16x8*)(xh + (size_t)o * 8) = v;
}

// ---- pack: Wt[(jb*128+r)*1024+k], r = (hl>>4)*64 + g*16 + (hl&15),
//      n = g*512 + jb*32 + hl. Coalesced via LDS transpose tile. ----
__global__ void pack_w(const float* __restrict__ Wx, const float* __restrict__ Wh,
                       __bf16* __restrict__ Wt) {
  __shared__ __bf16 T[128][72];                 // +8 pad
  const int jb = blockIdx.y;
  const int k0 = blockIdx.x * 64;
  const float* Wsrc = (k0 < DH) ? (Wx + (size_t)k0 * 4 * DH)
                                : (Wh + (size_t)(k0 - DH) * 4 * DH);
  const int t = threadIdx.x;
  const int s = t & 31, kr0 = t >> 5;           // 32 seg-threads x 8 k-rows
  const int g = s >> 3, q = s & 7;
  const int r0 = (q >> 2) * 64 + g * 16 + (q & 3) * 4;
  #pragma unroll
  for (int it = 0; it < 8; ++it) {
    int kr = it * 8 + kr0;
    float4 f = *(const float4*)(Wsrc + (size_t)kr * 4 * DH + g * DH + jb * 32 + q * 4);
    T[r0 + 0][kr] = (__bf16)f.x;
    T[r0 + 1][kr] = (__bf16)f.y;
    T[r0 + 2][kr] = (__bf16)f.z;
    T[r0 + 3][kr] = (__bf16)f.w;
  }
  __syncthreads();
  #pragma unroll
  for (int it = 0; it < 4; ++it) {
    int lin = it * 256 + t;                     // 0..1023
    int r = lin >> 3, k8 = lin & 7;
    bf16x8 v;
    #pragma unroll
    for (int j = 0; j < 8; ++j) v[j] = T[r][k8 * 8 + j];
    *(bf16x8*)(Wt + (size_t)(jb * 128 + r) * KTOT + k0 + k8 * 8) = v;
  }
}

// ---- main fused GEMM, m97 structure + XOR swizzle ----
__global__ __launch_bounds__(256, 3) void lstm_gemm2(
    const __bf16* __restrict__ xh, const __bf16* __restrict__ Wt,
    const float* __restrict__ bx, const float* __restrict__ bh,
    const float* __restrict__ Cin, float* __restrict__ out) {
  __shared__ __attribute__((aligned(16))) __bf16 As[BM * BK];
  __shared__ __attribute__((aligned(16))) __bf16 Bs[BM * BK];

  const int tid  = threadIdx.x;
  const int lane = tid & 63;
  const int wave = tid >> 6;
  const int wm = wave >> 1, wn = wave & 1;
  const int jb   = blockIdx.x;
  const int row0 = blockIdx.y * BM;

  const __bf16* Bt = Wt + (size_t)jb * 128 * KTOT;

  // prefetch bias + C (latency hidden behind K-loop)
  const int hd = jb * 32 + wn * 16 + (lane & 15);
  float bias[4], cpv[4][4];
  #pragma unroll
  for (int g = 0; g < 4; ++g) bias[g] = bx[g * DH + hd] + bh[g * DH + hd];
  #pragma unroll
  for (int cm = 0; cm < 4; ++cm)
    #pragma unroll
    for (int i2 = 0; i2 < 4; ++i2)
      cpv[cm][i2] = Cin[(size_t)(row0 + wm * 64 + cm * 16 + (lane >> 4) * 4 + i2) * DH + hd];

  f32x4 acc[4][4];
  #pragma unroll
  for (int a_ = 0; a_ < 4; ++a_)
    #pragma unroll
    for (int b_ = 0; b_ < 4; ++b_) acc[a_][b_] = (f32x4)0.0f;

  for (int k0 = 0; k0 < KTOT; k0 += BK) {
    // stage A,B via async global->LDS, 16B/lane; chunk index XOR-swizzled by
    // (row&7) so fragment ds_read_b128 spreads over all 32 banks.
    #pragma unroll
    for (int it = 0; it < 4; ++it) {
      int lin = it * 256 + tid;
      int r = lin >> 3, c8 = lin & 7;
      int cs = c8 ^ (r & 7);
      gl_lds16(xh + (size_t)(row0 + r) * KTOT + k0 + cs * 8, &As[lin * 8]);
    }
    #pragma unroll
    for (int it = 0; it < 4; ++it) {
      int lin = it * 256 + tid;
      int r = lin >> 3, c8 = lin & 7;
      int cs = c8 ^ (r & 7);
      gl_lds16(Bt + (size_t)r * KTOT + k0 + cs * 8, &Bs[lin * 8]);
    }
    __syncthreads();

    #pragma unroll
    for (int ks = 0; ks < 2; ++ks) {
      const int q = lane >> 4;
      bf16x8 af[4], bfr[4];
      #pragma unroll
      for (int cm = 0; cm < 4; ++cm) {
        int row = wm * 64 + cm * 16 + (lane & 15);
        int cc = (ks * 4 + q) ^ (row & 7);
        af[cm] = *(const bf16x8*)&As[row * BK + cc * 8];
      }
      #pragma unroll
      for (int cn = 0; cn < 4; ++cn) {
        int row = wn * 64 + cn * 16 + (lane & 15);
        int cc = (ks * 4 + q) ^ (row & 7);
        bfr[cn] = *(const bf16x8*)&Bs[row * BK + cc * 8];
      }
      #pragma unroll
      for (int cm = 0; cm < 4; ++cm)
        #pragma unroll
        for (int cn = 0; cn < 4; ++cn)
          acc[cm][cn] = __builtin_amdgcn_mfma_f32_16x16x32_bf16(
              af[cm], bfr[cn], acc[cm][cn], 0, 0, 0);
    }
    __syncthreads();
  }

  // fused LSTM epilogue
  #pragma unroll
  for (int cm = 0; cm < 4; ++cm) {
    const int rbase = row0 + wm * 64 + cm * 16 + (lane >> 4) * 4;
    #pragma unroll
    for (int i2 = 0; i2 < 4; ++i2) {
      const size_t r = (size_t)(rbase + i2);
      float ig = sigf(acc[cm][0][i2] + bias[0]);
      float fg = sigf(acc[cm][1][i2] + bias[1]);
      float og = sigf(acc[cm][2][i2] + bias[2]);
      float gg = tanhf_(acc[cm][3][i2] + bias[3]);
      float cnew = fg * cpv[cm][i2] + ig * gg;
      float hnew = og * tanhf_(cnew);
      out[r * DH + hd] = cnew;
      out[(size_t)BROWS * DH + r * DH + hd] = hnew;
    }
  }
}

// ---- R3 fallback GEMM (fp32 A staging, proven) for 4MB <= ws < 68MB ----
__global__ __launch_bounds__(256, 3) void lstm_gemm(
    const float* __restrict__ x, const float* __restrict__ h,
    const __bf16* __restrict__ Wt, const float* __restrict__ bx,
    const float* __restrict__ bh, const float* __restrict__ Cin,
    float* __restrict__ out) {
  __shared__ __attribute__((aligned(16))) __bf16 As[BM * BK];
  __shared__ __attribute__((aligned(16))) __bf16 Bs[BM * BK];
  const int tid  = threadIdx.x;
  const int lane = tid & 63;
  const int wave = tid >> 6;
  const int wm = wave >> 1, wn = wave & 1;
  const int jb   = blockIdx.x;
  const int row0 = blockIdx.y * BM;
  const __bf16* Bt = Wt + (size_t)jb * 128 * KTOT;
  f32x4 acc[4][4];
  #pragma unroll
  for (int a_ = 0; a_ < 4; ++a_)
    #pragma unroll
    for (int b_ = 0; b_ < 4; ++b_) acc[a_][b_] = (f32x4)0.0f;
  for (int k0 = 0; k0 < KTOT; k0 += BK) {
    const float* Aptr = (k0 < DH) ? (x + (size_t)row0 * DH + k0)
                                  : (h + (size_t)row0 * DH + (k0 - DH));
    bf16x8 ta[4], tb[4];
    #pragma unroll
    for (int it = 0; it < 4; ++it) {
      int lin = it * 256 + tid;
      int r = lin >> 3, c8 = lin & 7;
      const float* src = Aptr + r * DH + c8 * 8;
      float4 f0 = *(const float4*)src;
      float4 f1 = *(const float4*)(src + 4);
      bf16x8 v;
      v[0] = (__bf16)f0.x; v[1] = (__bf16)f0.y; v[2] = (__bf16)f0.z; v[3] = (__bf16)f0.w;
      v[4] = (__bf16)f1.x; v[5] = (__bf16)f1.y; v[6] = (__bf16)f1.z; v[7] = (__bf16)f1.w;
      ta[it] = v;
      tb[it] = *(const bf16x8*)(Bt + (size_t)r * KTOT + k0 + c8 * 8);
    }
    #pragma unroll
    for (int it = 0; it < 4; ++it) {
      int lin = it * 256 + tid;
      *(bf16x8*)&As[lin * 8] = ta[it];
      *(bf16x8*)&Bs[lin * 8] = tb[it];
    }
    __syncthreads();
    #pragma unroll
    for (int ks = 0; ks < 2; ++ks) {
      const int ko = ks * 32 + (lane >> 4) * 8;
      bf16x8 af[4], bfr[4];
      #pragma unroll
      for (int cm = 0; cm < 4; ++cm)
        af[cm] = *(const bf16x8*)&As[(wm * 64 + cm * 16 + (lane & 15)) * BK + ko];
      #pragma unroll
      for (int cn = 0; cn < 4; ++cn)
        bfr[cn] = *(const bf16x8*)&Bs[(wn * 64 + cn * 16 + (lane & 15)) * BK + ko];
      #pragma unroll
      for (int cm = 0; cm < 4; ++cm)
        #pragma unroll
        for (int cn = 0; cn < 4; ++cn)
          acc[cm][cn] = __builtin_amdgcn_mfma_f32_16x16x32_bf16(
              af[cm], bfr[cn], acc[cm][cn], 0, 0, 0);
    }
    __syncthreads();
  }
  const int hd = jb * 32 + wn * 16 + (lane & 15);
  float bias[4];
  #pragma unroll
  for (int g2 = 0; g2 < 4; ++g2) bias[g2] = bx[g2 * DH + hd] + bh[g2 * DH + hd];
  #pragma unroll
  for (int cm = 0; cm < 4; ++cm) {
    const int rbase = row0 + wm * 64 + cm * 16 + (lane >> 4) * 4;
    #pragma unroll
    for (int i2 = 0; i2 < 4; ++i2) {
      const size_t r = (size_t)(rbase + i2);
      float ig = sigf(acc[cm][0][i2] + bias[0]);
      float fg = sigf(acc[cm][1][i2] + bias[1]);
      float og = sigf(acc[cm][2][i2] + bias[2]);
      float gg = tanhf_(acc[cm][3][i2] + bias[3]);
      float cp = Cin[r * DH + hd];
      float cnew = fg * cp + ig * gg;
      float hnew = og * tanhf_(cnew);
      out[r * DH + hd] = cnew;
      out[(size_t)BROWS * DH + r * DH + hd] = hnew;
    }
  }
}

__global__ void lstm_naive(const float* __restrict__ x, const float* __restrict__ Cin,
                           const float* __restrict__ h, const float* __restrict__ Wx,
                           const float* __restrict__ bxp, const float* __restrict__ Wh,
                           const float* __restrict__ bhp, float* __restrict__ out) {
  int idx = blockIdx.x * 256 + threadIdx.x;
  int r = idx >> 9, hd = idx & 511;
  float z[4];
  #pragma unroll
  for (int g = 0; g < 4; ++g) z[g] = bxp[g * DH + hd] + bhp[g * DH + hd];
  for (int k = 0; k < DH; ++k) {
    float xv = x[(size_t)r * DH + k];
    #pragma unroll
    for (int g = 0; g < 4; ++g) z[g] += xv * Wx[k * 4 * DH + g * DH + hd];
  }
  for (int k = 0; k < DH; ++k) {
    float hv = h[(size_t)r * DH + k];
    #pragma unroll
    for (int g = 0; g < 4; ++g) z[g] += hv * Wh[k * 4 * DH + g * DH + hd];
  }
  float ig = sigf(z[0]), fg = sigf(z[1]), og = sigf(z[2]), gg = tanhf_(z[3]);
  float cp = Cin[(size_t)r * DH + hd];
  float cnew = fg * cp + ig * gg;
  float hnew = og * tanhf_(cnew);
  out[(size_t)r * DH + hd] = cnew;
  out[(size_t)BROWS * DH + (size_t)r * DH + hd] = hnew;
}

extern "C" void kernel_launch(void* const* d_in, const int* in_sizes, int n_in,
                              void* d_out, int out_size, void* d_ws, size_t ws_size,
                              hipStream_t stream) {
  const float* x  = (const float*)d_in[0];
  const float* Ci = (const float*)d_in[1];
  const float* h  = (const float*)d_in[2];
  const float* Wx = (const float*)d_in[3];
  const float* bx = (const float*)d_in[4];
  const float* Wh = (const float*)d_in[5];
  const float* bh = (const float*)d_in[6];
  float* out = (float*)d_out;

  const size_t wt_bytes = (size_t)2048 * KTOT * sizeof(__bf16);          // 4 MB
  const size_t xh_bytes = (size_t)BROWS * KTOT * sizeof(__bf16);         // 64 MB

  if (ws_size >= wt_bytes + xh_bytes) {
    __bf16* Wt = (__bf16*)d_ws;
    __bf16* xh = (__bf16*)((char*)d_ws + wt_bytes);
    pack_w<<<dim3(16, 16), dim3(256), 0, stream>>>(Wx, Wh, Wt);
    conv_xh<<<dim3((BROWS * KTOT / 8) / 256), dim3(256), 0, stream>>>(x, h, xh);
    lstm_gemm2<<<dim3(16, BROWS / BM), dim3(256), 0, stream>>>(xh, Wt, bx, bh, Ci, out);
  } else if (ws_size >= wt_bytes) {
    __bf16* Wt = (__bf16*)d_ws;
    pack_w<<<dim3(16, 16), dim3(256), 0, stream>>>(Wx, Wh, Wt);
    lstm_gemm<<<dim3(16, BROWS / BM), dim3(256), 0, stream>>>(x, h, Wt, bx, bh, Ci, out);
  } else {
    lstm_naive<<<dim3((BROWS * DH) / 256), dim3(256), 0, stream>>>(
        x, Ci, h, Wx, bx, Wh, bh, out);
  }
}